// Round 9
// baseline (533.278 us; speedup 1.0000x reference)
//
#include <hip/hip_runtime.h>
#include <hip/hip_fp16.h>
#include <hip/hip_cooperative_groups.h>

namespace cg = cooperative_groups;

// Layout: per level, fp16 ROW-PAIR repack R[y][x] = half2(img[y][x], img[min(y+1,S-1)][x]).
// One bilinear quad = one 8-byte load, zero-padding folded into weights.
//
// Round 9: the dominant remaining cost is ~85us of launch gaps across 6
// dispatches (front kernels sum to ~115us but occupy ~200us of wall). Fuse
// {zero tables, repack, hist, cursor, partition} into ONE cooperative kernel
// with persistent blocks + grid.sync between phases (LDS = 46KB union).
// sample4/unsort4 stay separate (keep full occupancy for the gather phase).
// Fallback: if cooperative launch unavailable, run the round-8 multi-kernel
// path (identical shared __device__ bodies).

typedef unsigned int u32x2 __attribute__((ext_vector_type(2)));
typedef unsigned int u32x4 __attribute__((ext_vector_type(4)));
typedef float f32x4 __attribute__((ext_vector_type(4)));

#define K 1024                 // 32x32 uv bins
#define CHUNK 4096             // points per partition block == hist block
#define SEG (CHUNK * 256)      // 1048576 pts/segment
#define NXCD 8

__device__ __forceinline__ int binof(float u, float v) {
    int bx = min(max((int)(u * 32.0f), 0), 31);
    int by = min(max((int)(v * 32.0f), 0), 31);
    return by * 32 + bx;
}

__device__ __forceinline__ unsigned pack2(float lo, float hi) {
    __half2 h = __halves2half2(__float2half(lo), __float2half(hi));
    unsigned w;
    __builtin_memcpy(&w, &h, 4);
    return w;
}

// ---------------- shared phase bodies ----------------

__device__ __forceinline__ void repack_item(
    const float* __restrict__ l1, const float* __restrict__ l2,
    const float* __restrict__ l3, const float* __restrict__ l4,
    __half2* __restrict__ r1, __half2* __restrict__ r2,
    __half2* __restrict__ r3, __half2* __restrict__ r4, int e) {
    const int n1 = 2048 * 2048, n2 = 1024 * 1024, n3 = 512 * 512, n4 = 256 * 256;
    const float* __restrict__ src = nullptr;
    __half2* __restrict__ dst = nullptr;
    int S = 0, logS = 0, j = 0;
    if (e < n1) {
        src = l1; dst = r1; S = 2048; logS = 11; j = e;
    } else if (e < n1 + n2) {
        src = l2; dst = r2; S = 1024; logS = 10; j = e - n1;
    } else if (e < n1 + n2 + n3) {
        src = l3; dst = r3; S = 512; logS = 9; j = e - (n1 + n2);
    } else if (e < n1 + n2 + n3 + n4) {
        src = l4; dst = r4; S = 256; logS = 8; j = e - (n1 + n2 + n3);
    }
    if (src) {
        int y = j >> logS;  // j..j+3 same row (j%4==0, S%4==0)
        f32x4 a = *(const f32x4*)(src + j);
        f32x4 b = *(const f32x4*)(src + ((y < S - 1) ? (j + S) : j));
        u32x4 o = {pack2(a.x, b.x), pack2(a.y, b.y), pack2(a.z, b.z),
                   pack2(a.w, b.w)};
        *(u32x4*)(dst + j) = o;
    }
}

__device__ __forceinline__ void hist_body(const float2* __restrict__ uv,
                                          unsigned* __restrict__ seghist,
                                          unsigned* __restrict__ chist, int n,
                                          int c, unsigned* cnt) {
    int t = threadIdx.x;
    for (int b = t; b < K; b += 256) cnt[b] = 0u;
    __syncthreads();
    int base = c * CHUNK;
    int m = min(CHUNK, n - base);
    const f32x4* uv4 = (const f32x4*)(uv + base);
    int npair = m >> 1;
    for (int k2 = t; k2 < npair; k2 += 256) {
        f32x4 q = __builtin_nontemporal_load(&uv4[k2]);
        atomicAdd(&cnt[binof(q.x, q.y)], 1u);
        atomicAdd(&cnt[binof(q.z, q.w)], 1u);
    }
    if ((m & 1) && t == 0) {
        float2 q = uv[base + m - 1];
        atomicAdd(&cnt[binof(q.x, q.y)], 1u);
    }
    __syncthreads();
    int seg = base / SEG;
    unsigned* gh = seghist + (size_t)seg * K;
    for (int b = t; b < K; b += 256) {
        unsigned v = cnt[b];
        if (chist) chist[(size_t)c * K + b] = v;  // non-atomic, coalesced
        if (v) atomicAdd(&gh[b], v);
    }
    __syncthreads();  // cnt reusable by caller's next iteration
}

__device__ __forceinline__ void cursor_body(const unsigned* __restrict__ seghist,
                                            const unsigned* __restrict__ chist,
                                            unsigned* __restrict__ cursor,
                                            int nchunks, int vb, unsigned* part,
                                            unsigned* base) {
    int seg = vb >> 6;  // 64 blocks per segment
    int grp = vb & 63;  // 16 bins per block
    const unsigned* h = seghist + (size_t)seg * K;
    int t = threadIdx.x;
    unsigned v0 = h[t * 4], v1 = h[t * 4 + 1], v2 = h[t * 4 + 2], v3 = h[t * 4 + 3];
    unsigned s1 = v0, s2 = v0 + v1, s3 = v0 + v1 + v2;
    part[t] = s3 + v3;
    __syncthreads();
    for (int off = 1; off < 256; off <<= 1) {
        unsigned x = (t >= off) ? part[t - off] : 0u;
        __syncthreads();
        part[t] += x;
        __syncthreads();
    }
    unsigned tb = (t > 0) ? part[t - 1] : 0u;
    unsigned segstart = (unsigned)seg * (unsigned)SEG;
    base[t * 4] = segstart + tb;
    base[t * 4 + 1] = segstart + tb + s1;
    base[t * 4 + 2] = segstart + tb + s2;
    base[t * 4 + 3] = segstart + tb + s3;
    __syncthreads();
    // chunk-axis scans: 4 waves x 4 bins, wave-shuffle scan (no barriers)
    int wave = t >> 6, lane = t & 63;
    int c0 = seg * (SEG / CHUNK);
    for (int j = wave; j < 16; j += 4) {
        int b = grp * 16 + j;
        unsigned run = 0;
        for (int r = 0; r < 4; ++r) {  // 4 x 64 = 256 chunks per segment
            int c = r * 64 + lane;
            unsigned v = (c0 + c < nchunks) ? chist[(size_t)(c0 + c) * K + b] : 0u;
            unsigned x = v;
            for (int d = 1; d < 64; d <<= 1) {
                unsigned y = __shfl_up(x, d);
                if (lane >= d) x += y;
            }
            cursor[((size_t)seg * K + b) * 256 + c] = base[b] + (x - v) + run;
            run += __shfl(x, 63);
        }
    }
    __syncthreads();  // part/base reusable by caller's next iteration
}

__device__ __forceinline__ void partition_body(
    const float2* __restrict__ uv, const unsigned* __restrict__ chist,
    const unsigned* __restrict__ cursor, float2* __restrict__ uv_s,
    unsigned* __restrict__ invp, int n, int c, float2* ssort, unsigned* cnt,
    unsigned* lbase, unsigned* gdiff, unsigned* part) {
    int t = threadIdx.x;
    int cb = c * CHUNK;
    int cnum = min(CHUNK, n - cb);
    int seg = c / (SEG / CHUNK);
    int cidx = c % (SEG / CHUNK);
    // chunk hist (coalesced 16B) + local exclusive scan -> lbase;
    // gdiff[b] = deterministic global base - lbase (no atomics anywhere)
    u32x4 hv = *(const u32x4*)(chist + (size_t)c * K + t * 4);
    {
        unsigned s1 = hv.x, s2 = hv.x + hv.y, s3 = hv.x + hv.y + hv.z;
        part[t] = s3 + hv.w;
        __syncthreads();
        for (int off = 1; off < 256; off <<= 1) {
            unsigned x = (t >= off) ? part[t - off] : 0u;
            __syncthreads();
            part[t] += x;
            __syncthreads();
        }
        unsigned tb = (t > 0) ? part[t - 1] : 0u;
        unsigned lb[4] = {tb, tb + s1, tb + s2, tb + s3};
        for (int j = 0; j < 4; ++j) {
            int b = t * 4 + j;
            lbase[b] = lb[j];
            gdiff[b] = cursor[((size_t)seg * K + b) * (SEG / CHUNK) + cidx] - lb[j];
            cnt[b] = 0u;
        }
    }
    __syncthreads();
    // rank pass: single uv read; stage into bin-sorted LDS slots; write inv
    const f32x4* uv4 = (const f32x4*)(uv + cb);
    int npair = cnum >> 1;
    for (int k2 = t; k2 < npair; k2 += 256) {
        f32x4 q = uv4[k2];
        int ba = binof(q.x, q.y);
        unsigned sa = lbase[ba] + atomicAdd(&cnt[ba], 1u);
        ssort[sa] = make_float2(q.x, q.y);
        int bb = binof(q.z, q.w);
        unsigned sb = lbase[bb] + atomicAdd(&cnt[bb], 1u);
        ssort[sb] = make_float2(q.z, q.w);
        if (invp) {
            u32x2 iv;
            iv.x = gdiff[ba] + sa;
            iv.y = gdiff[bb] + sb;
            *(u32x2*)(invp + cb + k2 * 2) = iv;
        }
    }
    if ((cnum & 1) && t == 0) {
        float2 q = uv[cb + cnum - 1];
        int b = binof(q.x, q.y);
        unsigned s = lbase[b] + atomicAdd(&cnt[b], 1u);
        ssort[s] = q;
        if (invp) invp[cb + cnum - 1] = gdiff[b] + s;
    }
    __syncthreads();
    // emit coalesced (per-bin runs)
    for (int s = t; s < cnum; s += 256) {
        float2 q = ssort[s];
        int b = binof(q.x, q.y);
        uv_s[gdiff[b] + (unsigned)s] = q;
    }
}

// ---------------- fused cooperative front kernel ----------------
__global__ __launch_bounds__(256) void fused_front_kernel(
    const float* __restrict__ l1, const float* __restrict__ l2,
    const float* __restrict__ l3, const float* __restrict__ l4,
    __half2* __restrict__ r1, __half2* __restrict__ r2,
    __half2* __restrict__ r3, __half2* __restrict__ r4,
    const float2* __restrict__ uv, unsigned* __restrict__ seghist,
    unsigned* __restrict__ chist, unsigned* __restrict__ cursor,
    float2* __restrict__ uv_s, unsigned* __restrict__ invp, int n, int pinned,
    int nchunks, int nseg, unsigned zero4) {
    __shared__ __align__(16) unsigned char smem[46080];
    cg::grid_group grid = cg::this_grid();
    const int nb = gridDim.x;
    const int blk = blockIdx.x;
    const int t = threadIdx.x;
    // Z: zero chist+seghist (contiguous, 16B-aligned)
    {
        u32x4* z = (u32x4*)chist;
        u32x4 zv = {0u, 0u, 0u, 0u};
        for (size_t i = (size_t)blk * 256 + t; i < (size_t)zero4;
             i += (size_t)nb * 256)
            z[i] = zv;
    }
    grid.sync();
    // A: repack (independent of hist -> same phase region)
    {
        const int items = (2048 * 2048 + 1024 * 1024 + 512 * 512 + 256 * 256) >> 10;
        for (int vb = blk; vb < items; vb += nb)
            repack_item(l1, l2, l3, l4, r1, r2, r3, r4, (vb * 256 + t) * 4);
    }
    // H: per-chunk histogram
    {
        unsigned* cnt = (unsigned*)smem;
        for (int c = blk; c < nchunks; c += nb)
            hist_body(uv, seghist, chist, n, c, cnt);
    }
    grid.sync();
    // C: deterministic cursor table
    {
        unsigned* part = (unsigned*)smem;
        unsigned* base = (unsigned*)(smem + 1024);
        for (int vb = blk; vb < nseg * 64; vb += nb)
            cursor_body(seghist, chist, cursor, nchunks, vb, part, base);
    }
    grid.sync();
    // P: partition (XCD-pinned; nb % 8 == 0 so blk%8 is iteration-invariant)
    {
        float2* ssort = (float2*)smem;
        unsigned* cnt = (unsigned*)(smem + 32768);
        unsigned* lbase = (unsigned*)(smem + 36864);
        unsigned* gdiff = (unsigned*)(smem + 40960);
        unsigned* part = (unsigned*)(smem + 45056);
        for (int vc = blk; vc < nchunks; vc += nb) {
            int c = pinned ? ((vc % NXCD) * (SEG / CHUNK) + vc / NXCD) : vc;
            partition_body(uv, chist, cursor, uv_s, invp, n, c, ssort, cnt,
                           lbase, gdiff, part);
            __syncthreads();
        }
    }
}

// ---------------- standalone fallback kernels (round-8 path) ----------------
__global__ __launch_bounds__(256) void repack_hist_kernel(
    const float* __restrict__ l1, const float* __restrict__ l2,
    const float* __restrict__ l3, const float* __restrict__ l4,
    __half2* __restrict__ r1, __half2* __restrict__ r2,
    __half2* __restrict__ r3, __half2* __restrict__ r4,
    const float2* __restrict__ uv, unsigned* __restrict__ seghist,
    unsigned* __restrict__ chist, int n) {
    repack_item(l1, l2, l3, l4, r1, r2, r3, r4,
                (blockIdx.x * 256 + threadIdx.x) * 4);
    if (seghist == nullptr) return;
    int c = blockIdx.x;
    if (c * CHUNK >= n) return;
    __shared__ unsigned cnt[K];
    hist_body(uv, seghist, chist, n, c, cnt);
}

__global__ __launch_bounds__(256) void cursor_kernel(
    const unsigned* __restrict__ seghist, const unsigned* __restrict__ chist,
    unsigned* __restrict__ cursor, int nchunks) {
    __shared__ unsigned part[256];
    __shared__ unsigned base[K];
    cursor_body(seghist, chist, cursor, nchunks, blockIdx.x, part, base);
}

__global__ __launch_bounds__(256) void partition_kernel(
    const float2* __restrict__ uv, const unsigned* __restrict__ chist,
    const unsigned* __restrict__ cursor, float2* __restrict__ uv_s,
    unsigned* __restrict__ invp, int n, int pinned) {
    __shared__ float2 ssort[CHUNK];
    __shared__ unsigned cnt[K];
    __shared__ unsigned lbase[K];
    __shared__ unsigned gdiff[K];
    __shared__ unsigned part[256];
    int blk = blockIdx.x;
    int c = pinned ? ((blk % NXCD) * (SEG / CHUNK) + blk / NXCD) : blk;
    if (c * CHUNK >= n) return;
    partition_body(uv, chist, cursor, uv_s, invp, n, c, ssort, cnt, lbase,
                   gdiff, part);
}

// ---- bilinear tap from row-pair half2 texture ----
__device__ __forceinline__ float sample_level(const __half2* __restrict__ R,
                                              const int S, const float gx,
                                              const float gy) {
    const float halfS = 0.5f * (float)S;
    float x = (gx + 1.0f) * halfS - 0.5f;
    float y = (gy + 1.0f) * halfS - 0.5f;
    float xf = floorf(x), yf = floorf(y);
    float wx = x - xf, wy = y - yf;
    int x0 = (int)xf, y0 = (int)yf;

    int yc = min(max(y0, 0), S - 1);
    float wa = (y0 >= 0) ? (1.0f - wy) : wy;
    if (y0 < -1 || y0 >= S) wa = 0.0f;
    float wb = (y0 >= 0 && y0 < S - 1) ? wy : 0.0f;

    int xb = min(max(x0, 0), S - 2);
    bool xin = (x0 >= 0) && (x0 <= S - 2);
    float wxa = xin ? (1.0f - wx) : ((x0 == -1) ? wx : 0.0f);
    float wxb = xin ? wx : ((x0 == S - 1) ? (1.0f - wx) : 0.0f);

    uint2 q;
    __builtin_memcpy(&q, (const char*)(R + (size_t)yc * (size_t)S + xb), 8);
    __half2 ca = *(const __half2*)&q.x;
    __half2 cb = *(const __half2*)&q.y;
    float2 fa = __half22float2(ca);
    float2 fb = __half22float2(cb);
    float cola = fmaf(wa, fa.x, wb * fa.y);
    float colb = fmaf(wa, fb.x, wb * fb.y);
    return fmaf(wxa, cola, wxb * colb);
}

__device__ __forceinline__ float sample_point(const __half2* __restrict__ r1,
                                              const __half2* __restrict__ r2,
                                              const __half2* __restrict__ r3,
                                              const __half2* __restrict__ r4,
                                              float ux, float uy) {
    float gx = ux * 2.0f - 1.0f;
    float gy = uy * 2.0f - 1.0f;
    float acc = sample_level(r1, 2048, gx, gy);
    acc += sample_level(r2, 1024, gx, gy);
    acc += sample_level(r3, 512, gx, gy);
    acc += sample_level(r4, 256, gx, gy);
    return acc;
}

// ---- sample in sorted order -> val_s (fully coalesced) ----
__global__ __launch_bounds__(256) void lappyr_sample4(
    const float2* __restrict__ uv_s, const __half2* __restrict__ r1,
    const __half2* __restrict__ r2, const __half2* __restrict__ r3,
    const __half2* __restrict__ r4, float* __restrict__ val_s, int n,
    int pinned) {
    int blk = blockIdx.x;
    int sb = pinned ? ((blk % NXCD) * (SEG / 1024) + blk / NXCD) : blk;
    int base = sb * 1024 + threadIdx.x * 4;
    if (base + 3 < n) {
        const f32x4* u4 = (const f32x4*)(uv_s + base);
        f32x4 a = __builtin_nontemporal_load(u4);
        f32x4 b = __builtin_nontemporal_load(u4 + 1);
        f32x4 res;
        res.x = sample_point(r1, r2, r3, r4, a.x, a.y);
        res.y = sample_point(r1, r2, r3, r4, a.z, a.w);
        res.z = sample_point(r1, r2, r3, r4, b.x, b.y);
        res.w = sample_point(r1, r2, r3, r4, b.z, b.w);
        *(f32x4*)(val_s + base) = res;
    } else {
        for (int j = 0; j < 4; ++j) {
            int p = base + j;
            if (p < n) {
                float2 q = uv_s[p];
                val_s[p] = sample_point(r1, r2, r3, r4, q.x, q.y);
            }
        }
    }
}

// ---- out[p] = val_s[inv[p]] (random READS, pinned L2 window) ----
__global__ __launch_bounds__(256) void lappyr_unsort4(
    const unsigned* __restrict__ inv, const float* __restrict__ val_s,
    float* __restrict__ out, int n, int pinned) {
    int blk = blockIdx.x;
    int sb = pinned ? ((blk % NXCD) * (SEG / 1024) + blk / NXCD) : blk;
    int base = sb * 1024 + threadIdx.x * 4;
    if (base + 3 < n) {
        u32x4 iv = __builtin_nontemporal_load((const u32x4*)(inv + base));
        f32x4 res;
        res.x = val_s[iv.x];
        res.y = val_s[iv.y];
        res.z = val_s[iv.z];
        res.w = val_s[iv.w];
        __builtin_nontemporal_store(res, (f32x4*)(out + base));
    } else {
        for (int j = 0; j < 4; ++j) {
            int p = base + j;
            if (p < n) out[p] = val_s[inv[p]];
        }
    }
}

// ---- fallback A: unsorted sampling over repacked levels ----
__global__ __launch_bounds__(256) void lappyr_sample_kernel(
    const float2* __restrict__ uv, const __half2* __restrict__ r1,
    const __half2* __restrict__ r2, const __half2* __restrict__ r3,
    const __half2* __restrict__ r4, float* __restrict__ out, int n) {
    int i = blockIdx.x * blockDim.x + threadIdx.x;
    if (i >= n) return;
    float2 p = uv[i];
    out[i] = sample_point(r1, r2, r3, r4, p.x, p.y);
}

// ---- fallback B (ws too small): direct f32 sampling ----
__device__ __forceinline__ float bilin_f32(const float* __restrict__ img,
                                           const int S, const float gx,
                                           const float gy) {
    const float halfS = 0.5f * (float)S;
    float x = (gx + 1.0f) * halfS - 0.5f;
    float y = (gy + 1.0f) * halfS - 0.5f;
    float xf = floorf(x), yf = floorf(y);
    float wx = x - xf, wy = y - yf;
    int x0 = (int)xf, y0 = (int)yf, x1 = x0 + 1, y1 = y0 + 1;
    float ex0 = (x0 >= 0 && x0 < S) ? (1.0f - wx) : 0.0f;
    float ex1 = (x1 >= 0 && x1 < S) ? wx : 0.0f;
    float ey0 = (y0 >= 0 && y0 < S) ? (1.0f - wy) : 0.0f;
    float ey1 = (y1 >= 0 && y1 < S) ? wy : 0.0f;
    int xc0 = min(max(x0, 0), S - 1), xc1 = min(max(x1, 0), S - 1);
    int yc0 = min(max(y0, 0), S - 1), yc1 = min(max(y1, 0), S - 1);
    const float* r0 = img + (size_t)yc0 * S;
    const float* r1 = img + (size_t)yc1 * S;
    return ey0 * fmaf(ex0, r0[xc0], ex1 * r0[xc1]) +
           ey1 * fmaf(ex0, r1[xc0], ex1 * r1[xc1]);
}

__global__ __launch_bounds__(256) void lappyr_f32_kernel(
    const float2* __restrict__ uv, const float* __restrict__ l1,
    const float* __restrict__ l2, const float* __restrict__ l3,
    const float* __restrict__ l4, float* __restrict__ out, int n) {
    int i = blockIdx.x * blockDim.x + threadIdx.x;
    if (i >= n) return;
    float2 p = uv[i];
    float gx = p.x * 2.0f - 1.0f;
    float gy = p.y * 2.0f - 1.0f;
    float acc = bilin_f32(l1, 2048, gx, gy);
    acc += bilin_f32(l2, 1024, gx, gy);
    acc += bilin_f32(l3, 512, gx, gy);
    acc += bilin_f32(l4, 256, gx, gy);
    out[i] = acc;
}

extern "C" void kernel_launch(void* const* d_in, const int* in_sizes, int n_in,
                              void* d_out, int out_size, void* d_ws, size_t ws_size,
                              hipStream_t stream) {
    const float2* uv = (const float2*)d_in[0];
    const float* l1 = (const float*)d_in[1];
    const float* l2 = (const float*)d_in[2];
    const float* l3 = (const float*)d_in[3];
    const float* l4 = (const float*)d_in[4];
    float* out = (float*)d_out;
    int n = out_size;

    const size_t n1 = 2048u * 2048u, n2 = 1024u * 1024u, n3 = 512u * 512u,
                 n4 = 256u * 256u;
    const size_t ntot = n1 + n2 + n3 + n4;
    const size_t rep_bytes = ntot * sizeof(__half2);  // ~21.25 MiB

    int nseg = (n + SEG - 1) / SEG;
    int nchunks = (n + CHUNK - 1) / CHUNK;
    int cps = SEG / CHUNK;  // 256

    // deterministic tables (aliased into val slab; dead until sample4):
    //   chist[nseg*256][K] | seghist[nseg][K] | cursor[nseg][K][256]
    size_t chist_b = (size_t)nseg * cps * K * 4;
    size_t seg_b = (size_t)nseg * K * 4;
    size_t tbl = chist_b + seg_b + chist_b;
    size_t val_region = ((size_t)n * 4 > tbl) ? (size_t)n * 4 : tbl;

    size_t off_uvs = (rep_bytes + 255) & ~(size_t)255;
    size_t off_inv = off_uvs + (size_t)n * 8;
    size_t off_val = (off_inv + (size_t)n * 4 + 255) & ~(size_t)255;
    size_t need2 = off_val + val_region;

    int repack_blocks = (int)((ntot / 4 + 255) / 256);

    if (ws_size >= rep_bytes) {
        char* ws = (char*)d_ws;
        __half2* r1 = (__half2*)ws;
        __half2* r2 = r1 + n1;
        __half2* r3 = r2 + n2;
        __half2* r4 = r3 + n3;
        int pinned = (n == NXCD * SEG) ? 1 : 0;
        if (ws_size >= need2 && n > 0) {
            float2* uv_s = (float2*)(ws + off_uvs);
            unsigned* inv = (unsigned*)(ws + off_inv);
            float* val_s = (float*)(ws + off_val);
            unsigned* chist = (unsigned*)(ws + off_val);
            unsigned* seghist = (unsigned*)(ws + off_val + chist_b);
            unsigned* cursor = (unsigned*)(ws + off_val + chist_b + seg_b);
            unsigned zero4 = (unsigned)((chist_b + seg_b) / 16);

            // cooperative grid size (cached): blocks/CU x CUs, multiple of 8
            static int coop_grid = -2;
            if (coop_grid == -2) {
                int nbk = 0;
                hipError_t oe = hipOccupancyMaxActiveBlocksPerMultiprocessor(
                    &nbk, fused_front_kernel, 256, (size_t)0);
                int ncu = 256;
                hipDeviceProp_t prop;
                int dev = 0;
                if (hipGetDevice(&dev) == hipSuccess &&
                    hipGetDeviceProperties(&prop, dev) == hipSuccess)
                    ncu = prop.multiProcessorCount;
                if (oe != hipSuccess || nbk < 1) {
                    coop_grid = -1;  // occupancy query failed -> no coop
                } else {
                    long g = (long)nbk * ncu;
                    if (g > 2048) g = 2048;
                    g &= ~7L;  // keep blk%8 invariant under persistent stride
                    coop_grid = (g >= 8) ? (int)g : -1;
                }
            }
            bool coop_ok = false;
            if (coop_grid > 0) {
                const float* a_l1 = l1; const float* a_l2 = l2;
                const float* a_l3 = l3; const float* a_l4 = l4;
                __half2* a_r1 = r1; __half2* a_r2 = r2;
                __half2* a_r3 = r3; __half2* a_r4 = r4;
                const float2* a_uv = uv;
                unsigned* a_seg = seghist; unsigned* a_ch = chist;
                unsigned* a_cur = cursor;
                float2* a_uvs = uv_s; unsigned* a_inv = inv;
                int a_n = n, a_pin = pinned, a_nch = nchunks, a_nseg = nseg;
                unsigned a_z4 = zero4;
                void* kargs[] = {&a_l1, &a_l2, &a_l3, &a_l4, &a_r1, &a_r2,
                                 &a_r3, &a_r4, &a_uv, &a_seg, &a_ch, &a_cur,
                                 &a_uvs, &a_inv, &a_n, &a_pin, &a_nch, &a_nseg,
                                 &a_z4};
                hipError_t ce = hipLaunchCooperativeKernel(
                    fused_front_kernel, dim3(coop_grid), dim3(256), kargs, 0u,
                    stream);
                coop_ok = (ce == hipSuccess);
            }
            if (!coop_ok) {
                // round-8 multi-kernel path (identical bodies)
                (void)hipMemsetAsync(chist, 0, chist_b + seg_b, stream);
                int ga = max(repack_blocks, nchunks);
                repack_hist_kernel<<<ga, 256, 0, stream>>>(
                    l1, l2, l3, l4, r1, r2, r3, r4, uv, seghist, chist, n);
                cursor_kernel<<<nseg * 64, 256, 0, stream>>>(seghist, chist,
                                                             cursor, nchunks);
                partition_kernel<<<nchunks, 256, 0, stream>>>(uv, chist, cursor,
                                                              uv_s, inv, n,
                                                              pinned);
            }
            int nb4 = (n + 1023) / 1024;
            lappyr_sample4<<<nb4, 256, 0, stream>>>(uv_s, r1, r2, r3, r4, val_s,
                                                    n, pinned);
            lappyr_unsort4<<<nb4, 256, 0, stream>>>(inv, val_s, out, n, pinned);
        } else {
            repack_hist_kernel<<<repack_blocks, 256, 0, stream>>>(
                l1, l2, l3, l4, r1, r2, r3, r4, uv, nullptr, nullptr, n);
            lappyr_sample_kernel<<<(n + 255) / 256, 256, 0, stream>>>(
                uv, r1, r2, r3, r4, out, n);
        }
    } else {
        lappyr_f32_kernel<<<(n + 255) / 256, 256, 0, stream>>>(uv, l1, l2, l3, l4,
                                                               out, n);
    }
}

// Round 10
// 512.362 us; speedup vs baseline: 1.0408x; 1.0408x over previous
//
#include <hip/hip_runtime.h>
#include <hip/hip_fp16.h>

// Layout: per level, fp16 ROW-PAIR repack R[y][x] = half2(img[y][x], img[min(y+1,S-1)][x]).
// One bilinear quad = one 8-byte load, zero-padding folded into weights.
//
// Round 10: REVERT round-9 coop fusion (46KB union LDS capped all phases at
// ~2 blocks/CU -> 3x slower). Back to round-8 split pipeline with cuts:
//  - seghist + memset ELIMINATED: cursor2 (1 block x 1024 thr per segment)
//    derives bin totals from chist itself (pass1), wave-scans 1024 bins
//    (2 barriers), streams cursor rows (pass2, L2-hot).
//  - cursor layout transposed to [seg][chunk][bin]: writes AND partition's
//    reads are contiguous 4KB rows (was 1KB-stride, 1024 lines/block).
//  - CHUNK 4096->2048: partition LDS 46->28KB -> ~5 blocks/CU (was 2,
//    occupancy 25% = the measured bottleneck).
//  - 16-barrier Hillis-Steele -> wave __shfl_up scan (4 barriers/chunk).
// 5 dispatches: repack_hist, cursor2, partition, sample4, unsort4.

typedef unsigned int u32x2 __attribute__((ext_vector_type(2)));
typedef unsigned int u32x4 __attribute__((ext_vector_type(4)));
typedef float f32x4 __attribute__((ext_vector_type(4)));

#define K 1024                 // 32x32 uv bins
#define CHUNK 2048             // points per partition block == hist block
#define CPS 512                // chunks per segment (SEG/CHUNK)
#define SEG (CHUNK * CPS)      // 1048576 pts/segment
#define NXCD 8

__device__ __forceinline__ int binof(float u, float v) {
    int bx = min(max((int)(u * 32.0f), 0), 31);
    int by = min(max((int)(v * 32.0f), 0), 31);
    return by * 32 + bx;
}

__device__ __forceinline__ unsigned pack2(float lo, float hi) {
    __half2 h = __halves2half2(__float2half(lo), __float2half(hi));
    unsigned w;
    __builtin_memcpy(&w, &h, 4);
    return w;
}

__device__ __forceinline__ void repack_item(
    const float* __restrict__ l1, const float* __restrict__ l2,
    const float* __restrict__ l3, const float* __restrict__ l4,
    __half2* __restrict__ r1, __half2* __restrict__ r2,
    __half2* __restrict__ r3, __half2* __restrict__ r4, int e) {
    const int n1 = 2048 * 2048, n2 = 1024 * 1024, n3 = 512 * 512, n4 = 256 * 256;
    const float* __restrict__ src = nullptr;
    __half2* __restrict__ dst = nullptr;
    int S = 0, logS = 0, j = 0;
    if (e < n1) {
        src = l1; dst = r1; S = 2048; logS = 11; j = e;
    } else if (e < n1 + n2) {
        src = l2; dst = r2; S = 1024; logS = 10; j = e - n1;
    } else if (e < n1 + n2 + n3) {
        src = l3; dst = r3; S = 512; logS = 9; j = e - (n1 + n2);
    } else if (e < n1 + n2 + n3 + n4) {
        src = l4; dst = r4; S = 256; logS = 8; j = e - (n1 + n2 + n3);
    }
    if (src) {
        int y = j >> logS;  // j..j+3 same row (j%4==0, S%4==0)
        f32x4 a = *(const f32x4*)(src + j);
        f32x4 b = *(const f32x4*)(src + ((y < S - 1) ? (j + S) : j));
        u32x4 o = {pack2(a.x, b.x), pack2(a.y, b.y), pack2(a.z, b.z),
                   pack2(a.w, b.w)};
        *(u32x4*)(dst + j) = o;
    }
}

// ---- kernel A: repack all 4 levels (x4 vectorized) + per-chunk histogram ----
// NO seghist, NO atomics to global: chist rows are fully overwritten.
__global__ __launch_bounds__(256) void repack_hist_kernel(
    const float* __restrict__ l1, const float* __restrict__ l2,
    const float* __restrict__ l3, const float* __restrict__ l4,
    __half2* __restrict__ r1, __half2* __restrict__ r2,
    __half2* __restrict__ r3, __half2* __restrict__ r4,
    const float2* __restrict__ uv, unsigned* __restrict__ chist, int n) {
    repack_item(l1, l2, l3, l4, r1, r2, r3, r4,
                (blockIdx.x * 256 + threadIdx.x) * 4);
    if (chist == nullptr) return;
    int c = blockIdx.x;
    int base = c * CHUNK;
    if (base >= n) return;
    __shared__ unsigned cnt[K];
    int t = threadIdx.x;
    for (int b = t; b < K; b += 256) cnt[b] = 0u;
    __syncthreads();
    int m = min(CHUNK, n - base);
    const f32x4* uv4 = (const f32x4*)(uv + base);
    int npair = m >> 1;
    for (int k2 = t; k2 < npair; k2 += 256) {
        f32x4 q = __builtin_nontemporal_load(&uv4[k2]);
        atomicAdd(&cnt[binof(q.x, q.y)], 1u);
        atomicAdd(&cnt[binof(q.z, q.w)], 1u);
    }
    if ((m & 1) && t == 0) {
        float2 q = uv[base + m - 1];
        atomicAdd(&cnt[binof(q.x, q.y)], 1u);
    }
    __syncthreads();
    for (int b = t; b < K; b += 256) chist[(size_t)c * K + b] = cnt[b];
}

// ---- kernel A2: cursor2 -- one block (1024 thr) per segment, 1 bin/thread ----
// cursor[(seg*CPS + c)*K + b] = seg*SEG + excl_bins(totals)[b]
//                             + excl_chunks(chist[..][b])[c]
__global__ __launch_bounds__(1024) void cursor2_kernel(
    const unsigned* __restrict__ chist, unsigned* __restrict__ cursor,
    int nchunks) {
    int seg = blockIdx.x;
    int b = threadIdx.x;  // 1024 bins
    int c0 = seg * CPS;
    // pass 1: bin total over this segment's chunks (coalesced rows)
    unsigned tot = 0;
    for (int c = 0; c < CPS; ++c) {
        int cc = c0 + c;
        if (cc < nchunks) tot += chist[(size_t)cc * K + b];
    }
    // wave-inclusive scan over bins, then cross-wave prefix (2 barriers)
    unsigned incl = tot;
    int lane = b & 63, wave = b >> 6;  // 16 waves
    for (int d = 1; d < 64; d <<= 1) {
        unsigned y = __shfl_up(incl, d);
        if (lane >= d) incl += y;
    }
    __shared__ unsigned wtot[16];
    if (lane == 63) wtot[wave] = incl;
    __syncthreads();
    unsigned wpre = 0;
    for (int w = 0; w < 16; ++w)
        if (w < wave) wpre += wtot[w];
    unsigned run = (unsigned)seg * (unsigned)SEG + wpre + (incl - tot);
    // pass 2: stream cursor rows (coalesced; chist re-read is L2-hot)
    for (int c = 0; c < CPS; ++c) {
        cursor[((size_t)seg * CPS + c) * K + b] = run;
        int cc = c0 + c;
        if (cc < nchunks) run += chist[(size_t)cc * K + b];
    }
}

// ---- kernel B: partition -> bin-sorted uv + inverse perm (atomic-free) ----
__global__ __launch_bounds__(256) void partition_kernel(
    const float2* __restrict__ uv, const unsigned* __restrict__ chist,
    const unsigned* __restrict__ cursor, float2* __restrict__ uv_s,
    unsigned* __restrict__ invp, int n, int pinned) {
    __shared__ float2 ssort[CHUNK];   // 16 KB
    __shared__ unsigned cnt[K];       // 4 KB
    __shared__ unsigned lbase[K];     // 4 KB
    __shared__ unsigned gdiff[K];     // 4 KB
    __shared__ unsigned wsum[4];
    int t = threadIdx.x;
    int blk = blockIdx.x;
    int c = pinned ? ((blk % NXCD) * CPS + blk / NXCD) : blk;
    int cb = c * CHUNK;
    if (cb >= n) return;
    int cnum = min(CHUNK, n - cb);
    int seg = c / CPS;
    int cidx = c % CPS;

    // chunk hist row (coalesced 16B) + wave-scan -> lbase; cursor row -> gdiff
    u32x4 hv = *(const u32x4*)(chist + (size_t)c * K + t * 4);
    {
        unsigned s1 = hv.x, s2 = hv.x + hv.y, s3 = hv.x + hv.y + hv.z;
        unsigned tot = s3 + hv.w;
        unsigned incl = tot;
        int lane = t & 63, wave = t >> 6;  // 4 waves x 256 bins
        for (int d = 1; d < 64; d <<= 1) {
            unsigned y = __shfl_up(incl, d);
            if (lane >= d) incl += y;
        }
        if (lane == 63) wsum[wave] = incl;
        __syncthreads();
        unsigned wpre = 0;
        for (int w = 0; w < 4; ++w)
            if (w < wave) wpre += wsum[w];
        unsigned tb = wpre + (incl - tot);
        const unsigned* crow = cursor + ((size_t)seg * CPS + cidx) * K;
        u32x4 cv = *(const u32x4*)(crow + t * 4);  // coalesced 4KB row
        unsigned lb0 = tb, lb1 = tb + s1, lb2 = tb + s2, lb3 = tb + s3;
        lbase[t * 4] = lb0;
        lbase[t * 4 + 1] = lb1;
        lbase[t * 4 + 2] = lb2;
        lbase[t * 4 + 3] = lb3;
        gdiff[t * 4] = cv.x - lb0;
        gdiff[t * 4 + 1] = cv.y - lb1;
        gdiff[t * 4 + 2] = cv.z - lb2;
        gdiff[t * 4 + 3] = cv.w - lb3;
        cnt[t * 4] = 0u;
        cnt[t * 4 + 1] = 0u;
        cnt[t * 4 + 2] = 0u;
        cnt[t * 4 + 3] = 0u;
    }
    __syncthreads();
    // rank pass: single uv read; stage into bin-sorted LDS slots; write inv
    const f32x4* uv4 = (const f32x4*)(uv + cb);
    int npair = cnum >> 1;
    for (int k2 = t; k2 < npair; k2 += 256) {
        f32x4 q = uv4[k2];
        int ba = binof(q.x, q.y);
        unsigned sa = lbase[ba] + atomicAdd(&cnt[ba], 1u);
        ssort[sa] = make_float2(q.x, q.y);
        int bb = binof(q.z, q.w);
        unsigned sb = lbase[bb] + atomicAdd(&cnt[bb], 1u);
        ssort[sb] = make_float2(q.z, q.w);
        if (invp) {
            u32x2 iv;
            iv.x = gdiff[ba] + sa;
            iv.y = gdiff[bb] + sb;
            __builtin_nontemporal_store(iv, (u32x2*)(invp + cb + k2 * 2));
        }
    }
    if ((cnum & 1) && t == 0) {
        float2 q = uv[cb + cnum - 1];
        int b = binof(q.x, q.y);
        unsigned s = lbase[b] + atomicAdd(&cnt[b], 1u);
        ssort[s] = q;
        if (invp) invp[cb + cnum - 1] = gdiff[b] + s;
    }
    __syncthreads();
    // emit coalesced (per-bin runs)
    for (int s = t; s < cnum; s += 256) {
        float2 q = ssort[s];
        int b = binof(q.x, q.y);
        uv_s[gdiff[b] + (unsigned)s] = q;
    }
}

// ---- bilinear tap from row-pair half2 texture ----
__device__ __forceinline__ float sample_level(const __half2* __restrict__ R,
                                              const int S, const float gx,
                                              const float gy) {
    const float halfS = 0.5f * (float)S;
    float x = (gx + 1.0f) * halfS - 0.5f;
    float y = (gy + 1.0f) * halfS - 0.5f;
    float xf = floorf(x), yf = floorf(y);
    float wx = x - xf, wy = y - yf;
    int x0 = (int)xf, y0 = (int)yf;

    int yc = min(max(y0, 0), S - 1);
    float wa = (y0 >= 0) ? (1.0f - wy) : wy;
    if (y0 < -1 || y0 >= S) wa = 0.0f;
    float wb = (y0 >= 0 && y0 < S - 1) ? wy : 0.0f;

    int xb = min(max(x0, 0), S - 2);
    bool xin = (x0 >= 0) && (x0 <= S - 2);
    float wxa = xin ? (1.0f - wx) : ((x0 == -1) ? wx : 0.0f);
    float wxb = xin ? wx : ((x0 == S - 1) ? (1.0f - wx) : 0.0f);

    uint2 q;
    __builtin_memcpy(&q, (const char*)(R + (size_t)yc * (size_t)S + xb), 8);
    __half2 ca = *(const __half2*)&q.x;
    __half2 cb = *(const __half2*)&q.y;
    float2 fa = __half22float2(ca);
    float2 fb = __half22float2(cb);
    float cola = fmaf(wa, fa.x, wb * fa.y);
    float colb = fmaf(wa, fb.x, wb * fb.y);
    return fmaf(wxa, cola, wxb * colb);
}

__device__ __forceinline__ float sample_point(const __half2* __restrict__ r1,
                                              const __half2* __restrict__ r2,
                                              const __half2* __restrict__ r3,
                                              const __half2* __restrict__ r4,
                                              float ux, float uy) {
    float gx = ux * 2.0f - 1.0f;
    float gy = uy * 2.0f - 1.0f;
    float acc = sample_level(r1, 2048, gx, gy);
    acc += sample_level(r2, 1024, gx, gy);
    acc += sample_level(r3, 512, gx, gy);
    acc += sample_level(r4, 256, gx, gy);
    return acc;
}

// ---- kernel C: sample in sorted order -> val_s (fully coalesced) ----
__global__ __launch_bounds__(256) void lappyr_sample4(
    const float2* __restrict__ uv_s, const __half2* __restrict__ r1,
    const __half2* __restrict__ r2, const __half2* __restrict__ r3,
    const __half2* __restrict__ r4, float* __restrict__ val_s, int n,
    int pinned) {
    int blk = blockIdx.x;
    int sb = pinned ? ((blk % NXCD) * (SEG / 1024) + blk / NXCD) : blk;
    int base = sb * 1024 + threadIdx.x * 4;
    if (base + 3 < n) {
        const f32x4* u4 = (const f32x4*)(uv_s + base);
        f32x4 a = __builtin_nontemporal_load(u4);
        f32x4 b = __builtin_nontemporal_load(u4 + 1);
        f32x4 res;
        res.x = sample_point(r1, r2, r3, r4, a.x, a.y);
        res.y = sample_point(r1, r2, r3, r4, a.z, a.w);
        res.z = sample_point(r1, r2, r3, r4, b.x, b.y);
        res.w = sample_point(r1, r2, r3, r4, b.z, b.w);
        *(f32x4*)(val_s + base) = res;
    } else {
        for (int j = 0; j < 4; ++j) {
            int p = base + j;
            if (p < n) {
                float2 q = uv_s[p];
                val_s[p] = sample_point(r1, r2, r3, r4, q.x, q.y);
            }
        }
    }
}

// ---- kernel D: out[p] = val_s[inv[p]] (random READS, pinned L2 window) ----
__global__ __launch_bounds__(256) void lappyr_unsort4(
    const unsigned* __restrict__ inv, const float* __restrict__ val_s,
    float* __restrict__ out, int n, int pinned) {
    int blk = blockIdx.x;
    int sb = pinned ? ((blk % NXCD) * (SEG / 1024) + blk / NXCD) : blk;
    int base = sb * 1024 + threadIdx.x * 4;
    if (base + 3 < n) {
        u32x4 iv = __builtin_nontemporal_load((const u32x4*)(inv + base));
        f32x4 res;
        res.x = val_s[iv.x];
        res.y = val_s[iv.y];
        res.z = val_s[iv.z];
        res.w = val_s[iv.w];
        __builtin_nontemporal_store(res, (f32x4*)(out + base));
    } else {
        for (int j = 0; j < 4; ++j) {
            int p = base + j;
            if (p < n) out[p] = val_s[inv[p]];
        }
    }
}

// ---- fallback A: unsorted sampling over repacked levels ----
__global__ __launch_bounds__(256) void lappyr_sample_kernel(
    const float2* __restrict__ uv, const __half2* __restrict__ r1,
    const __half2* __restrict__ r2, const __half2* __restrict__ r3,
    const __half2* __restrict__ r4, float* __restrict__ out, int n) {
    int i = blockIdx.x * blockDim.x + threadIdx.x;
    if (i >= n) return;
    float2 p = uv[i];
    out[i] = sample_point(r1, r2, r3, r4, p.x, p.y);
}

// ---- fallback B (ws too small): direct f32 sampling ----
__device__ __forceinline__ float bilin_f32(const float* __restrict__ img,
                                           const int S, const float gx,
                                           const float gy) {
    const float halfS = 0.5f * (float)S;
    float x = (gx + 1.0f) * halfS - 0.5f;
    float y = (gy + 1.0f) * halfS - 0.5f;
    float xf = floorf(x), yf = floorf(y);
    float wx = x - xf, wy = y - yf;
    int x0 = (int)xf, y0 = (int)yf, x1 = x0 + 1, y1 = y0 + 1;
    float ex0 = (x0 >= 0 && x0 < S) ? (1.0f - wx) : 0.0f;
    float ex1 = (x1 >= 0 && x1 < S) ? wx : 0.0f;
    float ey0 = (y0 >= 0 && y0 < S) ? (1.0f - wy) : 0.0f;
    float ey1 = (y1 >= 0 && y1 < S) ? wy : 0.0f;
    int xc0 = min(max(x0, 0), S - 1), xc1 = min(max(x1, 0), S - 1);
    int yc0 = min(max(y0, 0), S - 1), yc1 = min(max(y1, 0), S - 1);
    const float* r0 = img + (size_t)yc0 * S;
    const float* r1 = img + (size_t)yc1 * S;
    return ey0 * fmaf(ex0, r0[xc0], ex1 * r0[xc1]) +
           ey1 * fmaf(ex0, r1[xc0], ex1 * r1[xc1]);
}

__global__ __launch_bounds__(256) void lappyr_f32_kernel(
    const float2* __restrict__ uv, const float* __restrict__ l1,
    const float* __restrict__ l2, const float* __restrict__ l3,
    const float* __restrict__ l4, float* __restrict__ out, int n) {
    int i = blockIdx.x * blockDim.x + threadIdx.x;
    if (i >= n) return;
    float2 p = uv[i];
    float gx = p.x * 2.0f - 1.0f;
    float gy = p.y * 2.0f - 1.0f;
    float acc = bilin_f32(l1, 2048, gx, gy);
    acc += bilin_f32(l2, 1024, gx, gy);
    acc += bilin_f32(l3, 512, gx, gy);
    acc += bilin_f32(l4, 256, gx, gy);
    out[i] = acc;
}

extern "C" void kernel_launch(void* const* d_in, const int* in_sizes, int n_in,
                              void* d_out, int out_size, void* d_ws, size_t ws_size,
                              hipStream_t stream) {
    const float2* uv = (const float2*)d_in[0];
    const float* l1 = (const float*)d_in[1];
    const float* l2 = (const float*)d_in[2];
    const float* l3 = (const float*)d_in[3];
    const float* l4 = (const float*)d_in[4];
    float* out = (float*)d_out;
    int n = out_size;

    const size_t n1 = 2048u * 2048u, n2 = 1024u * 1024u, n3 = 512u * 512u,
                 n4 = 256u * 256u;
    const size_t ntot = n1 + n2 + n3 + n4;
    const size_t rep_bytes = ntot * sizeof(__half2);  // ~21.25 MiB

    int nseg = (n + SEG - 1) / SEG;
    int nchunks = (n + CHUNK - 1) / CHUNK;

    // tables aliased into val slab (dead until sample4):
    //   chist[nseg*CPS][K] | cursor[nseg*CPS][K]   (16.8 MB each at n=8M)
    size_t chist_b = (size_t)nseg * CPS * K * 4;
    size_t tbl = chist_b * 2;
    size_t val_region = ((size_t)n * 4 > tbl) ? (size_t)n * 4 : tbl;

    size_t off_uvs = (rep_bytes + 255) & ~(size_t)255;
    size_t off_inv = off_uvs + (size_t)n * 8;
    size_t off_val = (off_inv + (size_t)n * 4 + 255) & ~(size_t)255;
    size_t need2 = off_val + val_region;

    int repack_blocks = (int)((ntot / 4 + 255) / 256);

    if (ws_size >= rep_bytes) {
        char* ws = (char*)d_ws;
        __half2* r1 = (__half2*)ws;
        __half2* r2 = r1 + n1;
        __half2* r3 = r2 + n2;
        __half2* r4 = r3 + n3;
        int pinned = (n == NXCD * SEG) ? 1 : 0;
        if (ws_size >= need2 && n > 0) {
            float2* uv_s = (float2*)(ws + off_uvs);
            unsigned* inv = (unsigned*)(ws + off_inv);
            float* val_s = (float*)(ws + off_val);
            unsigned* chist = (unsigned*)(ws + off_val);
            unsigned* cursor = (unsigned*)(ws + off_val + chist_b);
            int ga = max(repack_blocks, nchunks);
            repack_hist_kernel<<<ga, 256, 0, stream>>>(l1, l2, l3, l4, r1, r2,
                                                       r3, r4, uv, chist, n);
            cursor2_kernel<<<nseg, 1024, 0, stream>>>(chist, cursor, nchunks);
            partition_kernel<<<nchunks, 256, 0, stream>>>(uv, chist, cursor,
                                                          uv_s, inv, n, pinned);
            int nb4 = (n + 1023) / 1024;
            lappyr_sample4<<<nb4, 256, 0, stream>>>(uv_s, r1, r2, r3, r4, val_s,
                                                    n, pinned);
            lappyr_unsort4<<<nb4, 256, 0, stream>>>(inv, val_s, out, n, pinned);
        } else {
            repack_hist_kernel<<<repack_blocks, 256, 0, stream>>>(
                l1, l2, l3, l4, r1, r2, r3, r4, uv, nullptr, n);
            lappyr_sample_kernel<<<(n + 255) / 256, 256, 0, stream>>>(
                uv, r1, r2, r3, r4, out, n);
        }
    } else {
        lappyr_f32_kernel<<<(n + 255) / 256, 256, 0, stream>>>(uv, l1, l2, l3, l4,
                                                               out, n);
    }
}